// Round 5
// baseline (101.806 us; speedup 1.0000x reference)
//
#include <hip/hip_runtime.h>
#include <math.h>

typedef _Float16 f16;
typedef _Float16 f16x8 __attribute__((ext_vector_type(8)));
typedef _Float16 f16x4 __attribute__((ext_vector_type(4)));
typedef float f32x4 __attribute__((ext_vector_type(4)));

#define BATCH 8
#define CHN   64
#define NPTS  8192
#define P2    192
#define GG    (P2 * P2)   // 36864
#define NCHUNK 128        // k-chunks per batch (64 pts each)

// ---------------------------------------------------------------------------
// k_mp: MS[c][c2][h] = sum_d Wq[h64+d][c]*Wk[h64+d][c2]   (h-contiguous float4)
//       P[h][o][c]   = sum_d Wout[o][h64+d]*Wv[h64+d][c]
// ---------------------------------------------------------------------------
__global__ __launch_bounds__(256) void k_mp(const float* __restrict__ Wq,
                                            const float* __restrict__ Wk,
                                            const float* __restrict__ Wv,
                                            const float* __restrict__ Wout,
                                            float* __restrict__ MS,
                                            float* __restrict__ P) {
    const int h     = blockIdx.x & 3;
    const int which = blockIdx.x >> 2;
    const int tid   = threadIdx.x;
    for (int e = 0; e < 16; e++) {
        int id = e * 256 + tid;          // id = r*64 + c2
        int r  = id >> 6, c2 = id & 63;
        float s = 0.0f;
        if (which == 0) {
#pragma unroll 8
            for (int d = 0; d < 64; d++)
                s += Wq[(h * 64 + d) * 64 + r] * Wk[(h * 64 + d) * 64 + c2];
            MS[(size_t)id * 4 + h] = s;
        } else {
#pragma unroll 8
            for (int d = 0; d < 64; d++)
                s += Wout[r * 256 + h * 64 + d] * Wv[(h * 64 + d) * 64 + c2];
            P[h * 4096 + id] = s;
        }
    }
}

// ---------------------------------------------------------------------------
// k_gram: per 64-pt chunk, MFMA Gram tile (4 quadrant waves) fully in regs,
// contract vs MS into 36 logits (rotation-bucketed), block-reduce in LDS,
// plain-store 36 partials. No atomics, no G in memory.
// LDS: union of stage tile T (24.6 KB) and reduce buffer SRED (38 KB).
// ---------------------------------------------------------------------------
__global__ __launch_bounds__(256, 2) void k_gram(const float* __restrict__ feat,
                                                 const float* __restrict__ MS,
                                                 float* __restrict__ pl) {
    const int kc  = blockIdx.x & (NCHUNK - 1);
    const int b   = blockIdx.x >> 7;
    const int n0  = kc * 64;
    const int tid = threadIdx.x;
    const int wid = tid >> 6, lane = tid & 63;
    const int l15 = lane & 15, l4 = lane >> 4;
    const int qp = (wid >> 1) * 96, qq = (wid & 1) * 96;

    __shared__ char smem[38016];               // T (24576 B) ⊔ SRED (38016 B)
    f16* T = (f16*)smem;                       // [192 rows][64 nn], XOR-swizzled
    float (*SRED)[36][66] = (float (*)[36][66])smem;
    __shared__ float fin[4][36];

    const float* fb = feat + (size_t)b * CHN * NPTS * 3;

    // stage 64 ch x 64 pts x 3 = 3072 float4 / 256 thr, transpose+cvt+swizzle
#pragma unroll
    for (int i = 0; i < 12; i++) {
        int idx = tid + i * 256;
        int c = idx / 48, j = idx - (idx / 48) * 48;
        float4 v = *(const float4*)(fb + ((size_t)c * NPTS + n0) * 3 + j * 4);
        float vv[4] = {v.x, v.y, v.z, v.w};
#pragma unroll
        for (int u = 0; u < 4; u++) {
            int e = j * 4 + u, nn = e / 3, t = e - 3 * (e / 3);
            int row = c * 3 + t;
            int bo = (row * 128 + nn * 2) ^ ((row & 7) << 4);
            *(f16*)(smem + bo) = (f16)vv[u];
        }
    }
    __syncthreads();

    f32x4 acc[6][6];
#pragma unroll
    for (int i = 0; i < 6; i++)
#pragma unroll
        for (int j = 0; j < 6; j++) acc[i][j] = (f32x4){0.f, 0.f, 0.f, 0.f};

#pragma unroll
    for (int ks = 0; ks < 2; ks++) {
        f16x8 af[6], bf[6];
#pragma unroll
        for (int mt = 0; mt < 6; mt++) {
            int row = qp + mt * 16 + l15;
            int bo = (row * 128 + ks * 64 + l4 * 16) ^ ((row & 7) << 4);
            af[mt] = *(const f16x8*)(smem + bo);
        }
#pragma unroll
        for (int nt = 0; nt < 6; nt++) {
            int row = qq + nt * 16 + l15;
            int bo = (row * 128 + ks * 64 + l4 * 16) ^ ((row & 7) << 4);
            bf[nt] = *(const f16x8*)(smem + bo);
        }
#pragma unroll
        for (int mt = 0; mt < 6; mt++)
#pragma unroll
            for (int nt = 0; nt < 6; nt++)
                acc[mt][nt] = __builtin_amdgcn_mfma_f32_16x16x32_f16(af[mt], bf[nt], acc[mt][nt], 0, 0, 0);
    }

    // ---- logit contraction ----
    // true t = (mt + r + l4) mod 3, true s = (nt + l15) mod 3
    float l[36];
#pragma unroll
    for (int i = 0; i < 36; i++) l[i] = 0.0f;
    int c2v[6];
#pragma unroll
    for (int nt = 0; nt < 6; nt++) { int q = qq + nt * 16 + l15; c2v[nt] = q / 3; }
#pragma unroll
    for (int mt = 0; mt < 6; mt++) {
#pragma unroll
        for (int r = 0; r < 4; r++) {
            int p = qp + mt * 16 + l4 * 4 + r;
            int c = p / 3;
            const f32x4* msrow = (const f32x4*)(MS + (size_t)c * 256);
#pragma unroll
            for (int nt = 0; nt < 6; nt++) {
                f32x4 ms = msrow[c2v[nt]];      // 4 heads
                float g = acc[mt][nt][r];
                const int ts = ((mt + r) % 3) * 3 + (nt % 3);
                l[ts]      = fmaf(ms[0], g, l[ts]);
                l[9 + ts]  = fmaf(ms[1], g, l[9 + ts]);
                l[18 + ts] = fmaf(ms[2], g, l[18 + ts]);
                l[27 + ts] = fmaf(ms[3], g, l[27 + ts]);
            }
        }
    }
    __syncthreads();    // T dead; SRED aliases it — all fragment reads done

    const int pt = l4 % 3, ps = l15 % 3;
    int rowmap[9];
#pragma unroll
    for (int tt = 0; tt < 3; tt++)
#pragma unroll
        for (int ss = 0; ss < 3; ss++)
            rowmap[tt * 3 + ss] = ((tt + pt) % 3) * 3 + ((ss + ps) % 3);
#pragma unroll
    for (int h = 0; h < 4; h++)
#pragma unroll
        for (int i9 = 0; i9 < 9; i9++)
            SRED[wid][h * 9 + rowmap[i9]][lane] = l[h * 9 + i9];
    __syncthreads();
    if (tid < 144) {
        int w = tid / 36, row = tid - (tid / 36) * 36;
        float s = 0.0f;
#pragma unroll 8
        for (int col = 0; col < 64; col++) s += SRED[w][row][col];
        fin[w][row] = s;
    }
    __syncthreads();
    if (tid < 36)
        pl[(size_t)(b * NCHUNK + kc) * 36 + tid]
            = fin[0][tid] + fin[1][tid] + fin[2][tid] + fin[3][tid];
}

// ---------------------------------------------------------------------------
// k_smax: per b, reduce NCHUNK partials per logit row; softmax over s;
// write w[b][36] (row = h*9 + t*3 + s)
// ---------------------------------------------------------------------------
__global__ __launch_bounds__(64) void k_smax(const float* __restrict__ pl,
                                             float* __restrict__ wbuf) {
    const int b   = blockIdx.x;
    const int tid = threadIdx.x;
    __shared__ float ls[36];
    if (tid < 36) {
        float s = 0.0f;
        for (int k = 0; k < NCHUNK; k++)
            s += pl[(size_t)(b * NCHUNK + k) * 36 + tid];
        ls[tid] = s;
    }
    __syncthreads();
    if (tid < 36) {
        const float inv = 0.07216878364870322f;   // 1/sqrt(192)
        int base = (tid / 3) * 3;                 // (h,t) row base
        float z0 = ls[base] * inv, z1 = ls[base + 1] * inv, z2 = ls[base + 2] * inv;
        float mx = fmaxf(z0, fmaxf(z1, z2));
        float e0 = expf(z0 - mx), e1 = expf(z1 - mx), e2 = expf(z2 - mx);
        wbuf[b * 36 + tid] = expf(ls[tid] * inv - mx) / (e0 + e1 + e2);
    }
}

// ---------------------------------------------------------------------------
// k_abig: Ab[b][p2][q2] = fp16( sum_h w[b][h][t][s] * P[h][o][c] )
// ---------------------------------------------------------------------------
__global__ __launch_bounds__(256) void k_abig(const float* __restrict__ wbuf,
                                              const float* __restrict__ P,
                                              f16* __restrict__ Ab) {
    int i = blockIdx.x * 256 + threadIdx.x;      // exactly BATCH*GG threads
    int b  = i / GG;
    int rr = i - b * GG;
    int p2 = rr / P2, q2 = rr - p2 * P2;
    int o = p2 / 3, t = p2 - 3 * (p2 / 3);
    int c = q2 / 3, s = q2 - 3 * (q2 / 3);
    float acc = 0.0f;
#pragma unroll
    for (int h = 0; h < 4; h++)
        acc = fmaf(wbuf[b * 36 + h * 9 + t * 3 + s], P[h * 4096 + o * 64 + c], acc);
    Ab[i] = (f16)acc;
}

// ---------------------------------------------------------------------------
// k_apply: out[b][o][n][t] = feat + sum_q2 Ab[p2][q2] * X[n][q2]
// Fused transpose-stage of feat into LDS X[32][200] fp16; MFMA; residual
// taken from X. A-fragments stream from L2.
// ---------------------------------------------------------------------------
__global__ __launch_bounds__(256, 4) void k_apply(const float* __restrict__ feat,
                                                  const f16* __restrict__ Ab,
                                                  float* __restrict__ out) {
    const int nb  = blockIdx.x & 255;
    const int b   = blockIdx.x >> 8;
    const int n0  = nb * 32;
    const int tid = threadIdx.x;
    const int wid = tid >> 6, lane = tid & 63;
    const int l15 = lane & 15, l4 = lane >> 4;

    __shared__ f16 X[32 * 200];          // [nn][q2], padded 192->200

    const float* fb = feat + (size_t)b * CHN * NPTS * 3;
    const f16* A = Ab + (size_t)b * GG;

#pragma unroll
    for (int i = 0; i < 6; i++) {
        int idx = tid + i * 256;
        int c = idx / 24, j = idx - (idx / 24) * 24;
        float4 v = *(const float4*)(fb + ((size_t)c * NPTS + n0) * 3 + j * 4);
        float vv[4] = {v.x, v.y, v.z, v.w};
#pragma unroll
        for (int u = 0; u < 4; u++) {
            int e = j * 4 + u, nn = e / 3, s = e - 3 * (e / 3);
            X[nn * 200 + c * 3 + s] = (f16)vv[u];
        }
    }
    __syncthreads();

    f32x4 acc[3][2];
#pragma unroll
    for (int i = 0; i < 3; i++)
#pragma unroll
        for (int j = 0; j < 2; j++) acc[i][j] = (f32x4){0.f, 0.f, 0.f, 0.f};

#pragma unroll
    for (int ks = 0; ks < 6; ks++) {
        f16x8 af[3], bf[2];
#pragma unroll
        for (int mt = 0; mt < 3; mt++) {
            int p2 = wid * 48 + mt * 16 + l15;
            af[mt] = *(const f16x8*)(A + (size_t)p2 * P2 + ks * 32 + l4 * 8);
        }
#pragma unroll
        for (int nt = 0; nt < 2; nt++) {
            int nl = nt * 16 + l15;
            bf[nt] = *(const f16x8*)&X[nl * 200 + ks * 32 + l4 * 8];
        }
#pragma unroll
        for (int mt = 0; mt < 3; mt++)
#pragma unroll
            for (int nt = 0; nt < 2; nt++)
                acc[mt][nt] = __builtin_amdgcn_mfma_f32_16x16x32_f16(af[mt], bf[nt], acc[mt][nt], 0, 0, 0);
    }

    float* ob = out + (size_t)b * CHN * NPTS * 3;
#pragma unroll
    for (int mt = 0; mt < 3; mt++) {
        int p2b = wid * 48 + mt * 16 + l4 * 4;
#pragma unroll
        for (int nt = 0; nt < 2; nt++) {
            int nl = nt * 16 + l15;
            f16x4 rx = *(const f16x4*)&X[nl * 200 + p2b];
#pragma unroll
            for (int r = 0; r < 4; r++) {
                int p2 = p2b + r;
                int o = p2 / 3, t = p2 - 3 * (p2 / 3);
                ob[((size_t)o * NPTS + n0 + nl) * 3 + t] = (float)rx[r] + acc[mt][nt][r];
            }
        }
    }
}

extern "C" void kernel_launch(void* const* d_in, const int* in_sizes, int n_in,
                              void* d_out, int out_size, void* d_ws, size_t ws_size,
                              hipStream_t stream) {
    const float* feat = (const float*)d_in[0];
    const float* Wq   = (const float*)d_in[2];
    const float* Wk   = (const float*)d_in[3];
    const float* Wv   = (const float*)d_in[4];
    const float* Wout = (const float*)d_in[5];
    float* out = (float*)d_out;

    char* w8 = (char*)d_ws;                    // total ws use: ~870 KB
    f16*   Ab   = (f16*)w8;                    // 589,824 B
    float* MS   = (float*)(w8 + 589824);       //  65,536 B
    float* P    = (float*)(w8 + 655360);       //  65,536 B
    float* pl   = (float*)(w8 + 720896);       // 147,456 B (1024 x 36)
    float* wbuf = (float*)(w8 + 868352);       //   1,152 B

    k_mp   <<<8,    256, 0, stream>>>(Wq, Wk, Wv, Wout, MS, P);
    k_gram <<<BATCH * NCHUNK, 256, 0, stream>>>(feat, MS, pl);
    k_smax <<<BATCH, 64, 0, stream>>>(pl, wbuf);
    k_abig <<<1152, 256, 0, stream>>>(wbuf, P, Ab);
    k_apply<<<2048, 256, 0, stream>>>(feat, Ab, out);
}